// Round 4
// baseline (389.564 us; speedup 1.0000x reference)
//
#include <hip/hip_runtime.h>
#include <hip/hip_fp16.h>

#define N_NODES 20000
#define N_EDGES 320000
#define DIM 256
// H=8 heads, C=32 channels/head

typedef _Float16 f16;
typedef unsigned int u32;
typedef f16 f16x8 __attribute__((ext_vector_type(8)));
typedef f16 f16x4 __attribute__((ext_vector_type(4)));
typedef float f32x4 __attribute__((ext_vector_type(4)));

#define GLL16(gsrc, ldst) __builtin_amdgcn_global_load_lds( \
    (const u32 __attribute__((address_space(1)))*)(gsrc),   \
    (u32 __attribute__((address_space(3)))*)(ldst), 16, 0, 0)

// ---- prep: 5 weights f32 (K x N) -> f16 transposed (N x K); pack biases; zero deg ----
__global__ void prep_all(const float* __restrict__ Wq, const float* __restrict__ Wk,
                         const float* __restrict__ Wv, const float* __restrict__ Ws,
                         const float* __restrict__ We,
                         const float* __restrict__ bq, const float* __restrict__ bk,
                         const float* __restrict__ bv, const float* __restrict__ bs,
                         f16* __restrict__ wtbase, float* __restrict__ biasAll,
                         int* __restrict__ deg) {
    if (blockIdx.x < 1280) {
        int gid = blockIdx.x * 256 + threadIdx.x;
        int w = gid >> 16;            // 0..4 : q,k,v,s,e
        int idx = gid & 65535;
        int k = idx >> 8, n = idx & 255;
        const float* W = (w == 0) ? Wq : (w == 1) ? Wk : (w == 2) ? Wv : (w == 3) ? Ws : We;
        wtbase[w * 65536 + n * 256 + k] = (f16)W[k * 256 + n];
    } else if (blockIdx.x < 1284) {
        int i = (blockIdx.x - 1280) * 256 + threadIdx.x;  // 0..1023
        int y = i >> 8, col = i & 255;
        const float* b = (y == 0) ? bq : (y == 1) ? bk : (y == 2) ? bv : bs;
        biasAll[i] = b[col];
    } else {
        int i = (blockIdx.x - 1284) * 256 + threadIdx.x;
        if (i < N_NODES) deg[i] = 0;
    }
}

// ---- GEMM v4: out[M x 256] = A[M x 256] @ W (+bias), N split in halves ----
// Block 512 thr = 8 waves; block tile 128 rows x 128 cols; wave = 16 rows x 128 cols.
// Per block: issue ALL A loads (full K, 16 dwordx4/lane) + ALL B staging (64 KB via
// global_load_lds) up front -> ONE barrier -> pure LDS+MFMA loop, no in-loop waits.
// One HBM-latency exposure per block; 2 blocks/CU (64 KB LDS) overlap each other.
// LDS layout: row nrel (0..127) x 32 16B-slots; logical k-chunk c stored at physical
// slot c ^ (nrel&31). Applied as pre-swizzled GLOBAL source (linear LDS dest, rule:
// global_load_lds writes base+lane*16) and the same XOR on the ds_read side.
// EDGE=1: A row gathered via eids (CSR slot order), C written sequentially to ef.
template<int EDGE>
__global__ __launch_bounds__(512, 4) void gemm_v4(
    const float* __restrict__ A, const f16* __restrict__ WTbase,
    const float* __restrict__ biasAll, const int* __restrict__ eids,
    f16* __restrict__ outF16, float* __restrict__ outF32, int M)
{
    __shared__ __align__(16) char lds[65536];
    const int tid = threadIdx.x;
    const int wave = tid >> 6, lane = tid & 63;
    const int l16 = lane & 15, lg = lane >> 4;
    const int y = blockIdx.y;
    const int outSel  = EDGE ? 4 : (y >> 1);
    const int colHalf = EDGE ? y : (y & 1);
    const f16* __restrict__ WT = WTbase + outSel * 65536 + colHalf * 128 * 256;
    const int rowBase = blockIdx.x * 128 + wave * 16;

    // ---- issue all A loads (longest latency first) ----
    const int slot = rowBase + l16;
    int arow;
    if (EDGE) arow = eids[slot];
    else      arow = (slot < M) ? slot : M - 1;
    const float* ap = A + (size_t)arow * DIM;
    f32x4 lo[8], hi[8];
#pragma unroll
    for (int ks = 0; ks < 8; ++ks) {
        lo[ks] = *(const f32x4*)(ap + ks * 32 + lg * 8);
        hi[ks] = *(const f32x4*)(ap + ks * 32 + lg * 8 + 4);
    }

    // ---- issue all B staging: 8 x 1KB per wave, pre-swizzled source ----
    {
        const int p = lane & 31;
#pragma unroll
        for (int r = 0; r < 8; ++r) {
            const int nrel = wave * 16 + r * 2 + (lane >> 5);
            const f16* src = WT + nrel * 256 + (p ^ (nrel & 31)) * 8;
            GLL16(src, &lds[(wave * 16 + r * 2) * 512]);
        }
    }

    // ---- convert A while stage drains ----
    f16x8 afr[8];
#pragma unroll
    for (int ks = 0; ks < 8; ++ks) {
#pragma unroll
        for (int j = 0; j < 4; ++j) {
            afr[ks][j]     = (f16)lo[ks][j];
            afr[ks][4 + j] = (f16)hi[ks][j];
        }
    }

    f32x4 acc[8];
#pragma unroll
    for (int c = 0; c < 8; ++c) acc[c] = (f32x4){0.f, 0.f, 0.f, 0.f};

    __syncthreads();   // single drain: B staged (and A long since converted)

#pragma unroll
    for (int ks = 0; ks < 8; ++ks) {
#pragma unroll
        for (int ct = 0; ct < 8; ++ct) {
            const int nrel = ct * 16 + l16;
            f16x8 b = *(const f16x8*)(lds + nrel * 512 + (((ks * 4 + lg) ^ (nrel & 31)) * 16));
            acc[ct] = __builtin_amdgcn_mfma_f32_16x16x32_f16(afr[ks], b, acc[ct], 0, 0, 0);
        }
    }

    // ---- epilogue: col = colHalf*128 + ct*16 + l16, row = rowBase + lg*4 + i ----
#pragma unroll
    for (int ct = 0; ct < 8; ++ct) {
        const int col = colHalf * 128 + ct * 16 + l16;
        const float bv = EDGE ? 0.f : biasAll[outSel * 256 + col];
#pragma unroll
        for (int i = 0; i < 4; ++i) {
            const int row = rowBase + lg * 4 + i;
            if (EDGE || row < M) {
                const float val = acc[ct][i] + bv;
                if (EDGE) {
                    outF16[(size_t)row * 256 + col] = (f16)val;   // CSR-slot order
                } else if (outSel < 3) {
                    (outF16 + (size_t)outSel * N_NODES * 256)[(size_t)row * 256 + col] = (f16)val;
                } else {
                    outF32[(size_t)row * 256 + col] = val;
                }
            }
        }
    }
}

// ---- CSR build (by dst) ----
__global__ void count_deg(const int* __restrict__ dst, int* __restrict__ deg) {
    int e = blockIdx.x * blockDim.x + threadIdx.x;
    if (e < N_EDGES) atomicAdd(&deg[dst[e]], 1);
}

__global__ __launch_bounds__(1024) void scan_deg(const int* __restrict__ deg,
                                                 int* __restrict__ rowptr,
                                                 int* __restrict__ cursor) {
    __shared__ int part[1024];
    const int t = threadIdx.x;
    const int CH = (N_NODES + 1023) / 1024; // 20
    const int base = t * CH;
    int s = 0;
    for (int i = 0; i < CH; ++i) { int n = base + i; if (n < N_NODES) s += deg[n]; }
    part[t] = s;
    __syncthreads();
    for (int off = 1; off < 1024; off <<= 1) {
        int v = (t >= off) ? part[t - off] : 0;
        __syncthreads();
        part[t] += v;
        __syncthreads();
    }
    int run = (t == 0) ? 0 : part[t - 1];
    for (int i = 0; i < CH; ++i) {
        int n = base + i;
        if (n < N_NODES) { int dn = deg[n]; rowptr[n] = run; cursor[n] = run; run += dn; }
    }
    if (t == 1023) rowptr[N_NODES] = part[1023]; // == E
}

__global__ void scatter_edges(const int* __restrict__ src, const int* __restrict__ dst,
                              int* __restrict__ cursor,
                              int* __restrict__ eids, int* __restrict__ srcs) {
    int e = blockIdx.x * blockDim.x + threadIdx.x;
    if (e < N_EDGES) {
        int p = atomicAdd(&cursor[dst[e]], 1);
        eids[p] = e;
        srcs[p] = src[e];
    }
}

// ---- fused softmax + aggregate: one wave per dst node ----
// ef and srcs are CSR-ordered -> sequential; only k/v are gathers (L2/L3-resident).
// lane l handles channels [4l, 4l+4); head h = l/8 spans lanes [8h, 8h+8).
__global__ __launch_bounds__(256) void aggregate(
    const f16* __restrict__ qf, const f16* __restrict__ kf, const f16* __restrict__ vf,
    const f16* __restrict__ ef, const int* __restrict__ srcs,
    const int* __restrict__ rowptr, float* __restrict__ out)
{
    const int wave = threadIdx.x >> 6;
    const int lane = threadIdx.x & 63;
    const int node = blockIdx.x * 4 + wave;
    if (node >= N_NODES) return;
    const int c0 = lane * 4;

    f32x4 qv;
    {
        f16x4 qh = *(const f16x4*)(qf + (size_t)node * 256 + c0);
        qv = (f32x4){(float)qh[0], (float)qh[1], (float)qh[2], (float)qh[3]};
    }
    float acc0 = 0.f, acc1 = 0.f, acc2 = 0.f, acc3 = 0.f, den = 0.f;
    const int beg = rowptr[node], end = rowptr[node + 1];

#define BODY(ii) {                                                              \
        const int src = srcs[ii];                                               \
        f16x4 eh = *(const f16x4*)(ef + (size_t)(ii) * 256 + c0);               \
        f16x4 kh = *(const f16x4*)(kf + (size_t)src * 256 + c0);                \
        f16x4 vh = *(const f16x4*)(vf + (size_t)src * 256 + c0);                \
        const float e0 = (float)eh[0], e1 = (float)eh[1];                       \
        const float e2 = (float)eh[2], e3 = (float)eh[3];                       \
        float d = qv[0] * ((float)kh[0] + e0) + qv[1] * ((float)kh[1] + e1)     \
                + qv[2] * ((float)kh[2] + e2) + qv[3] * ((float)kh[3] + e3);    \
        d += __shfl_xor(d, 1);                                                  \
        d += __shfl_xor(d, 2);                                                  \
        d += __shfl_xor(d, 4);                                                  \
        const float w_ = __expf(d * 0.1767766952966369f);                       \
        den += w_;                                                              \
        acc0 += w_ * ((float)vh[0] + e0);                                       \
        acc1 += w_ * ((float)vh[1] + e1);                                       \
        acc2 += w_ * ((float)vh[2] + e2);                                       \
        acc3 += w_ * ((float)vh[3] + e3);                                       \
    }

    int idx = beg;
    for (; idx + 1 < end; idx += 2) { BODY(idx); BODY(idx + 1); }
    if (idx < end) BODY(idx);
#undef BODY

    const float inv = 1.0f / (den + 1e-16f);
    const size_t ob = (size_t)node * 256 + c0;
    f32x4 o = *(f32x4*)(out + ob);              // holds skip from gemm_v4 outSel==3
    o[0] += acc0 * inv; o[1] += acc1 * inv; o[2] += acc2 * inv; o[3] += acc3 * inv;
    *(f32x4*)(out + ob) = o;
}

extern "C" void kernel_launch(void* const* d_in, const int* in_sizes, int n_in,
                              void* d_out, int out_size, void* d_ws, size_t ws_size,
                              hipStream_t stream) {
    const float* x   = (const float*)d_in[0];
    const int*   ei  = (const int*)d_in[1];     // [0..E): src, [E..2E): dst
    const float* ea  = (const float*)d_in[2];
    const float* Wq  = (const float*)d_in[3];
    const float* bq  = (const float*)d_in[4];
    const float* Wk  = (const float*)d_in[5];
    const float* bk  = (const float*)d_in[6];
    const float* Wv  = (const float*)d_in[7];
    const float* bv  = (const float*)d_in[8];
    const float* We  = (const float*)d_in[9];
    const float* Ws  = (const float*)d_in[10];
    const float* bs  = (const float*)d_in[11];
    float* out = (float*)d_out;

    const int* srcArr = ei;
    const int* dstArr = ei + N_EDGES;

    // workspace layout
    char* w = (char*)d_ws;
    size_t off = 0;
    f16* wtbase = (f16*)(w + off); off += 5 * 65536 * 2;            // q,k,v,s,e transposed
    f16* qf = (f16*)(w + off); off += (size_t)N_NODES * 256 * 2;
    f16* kf = (f16*)(w + off); off += (size_t)N_NODES * 256 * 2;
    f16* vf = (f16*)(w + off); off += (size_t)N_NODES * 256 * 2;
    f16* ef = (f16*)(w + off); off += (size_t)N_EDGES * 256 * 2;    // CSR-slot order
    int* deg    = (int*)(w + off); off += 80016;
    int* rowptr = (int*)(w + off); off += 80016;
    int* cursor = (int*)(w + off); off += 80016;
    int* eids   = (int*)(w + off); off += (size_t)N_EDGES * 4;
    int* srcs   = (int*)(w + off); off += (size_t)N_EDGES * 4;      // CSR-slot order
    float* biasAll = (float*)(w + off); off += 4 * 256 * 4;
    (void)ws_size; (void)n_in; (void)in_sizes; (void)out_size;

    // prep: weight transpose + bias pack + deg zero (one launch)
    prep_all<<<1284 + (N_NODES + 255) / 256, 256, 0, stream>>>(
        Wq, Wk, Wv, Ws, We, bq, bk, bv, bs, wtbase, biasAll, deg);

    // CSR build (must precede edge GEMM, which consumes eids)
    count_deg<<<(N_EDGES + 255) / 256, 256, 0, stream>>>(dstArr, deg);
    scan_deg<<<1, 1024, 0, stream>>>(deg, rowptr, cursor);
    scatter_edges<<<(N_EDGES + 255) / 256, 256, 0, stream>>>(srcArr, dstArr, cursor, eids, srcs);

    // GEMMs: node (4 outputs x 2 col-halves via grid.y) + edge (2 col-halves)
    dim3 gnode((N_NODES + 127) / 128, 8);
    gemm_v4<0><<<gnode, 512, 0, stream>>>(x, wtbase, biasAll, nullptr, qf, out, N_NODES);
    dim3 gedge(N_EDGES / 128, 2);
    gemm_v4<1><<<gedge, 512, 0, stream>>>(ea, wtbase, nullptr, eids, ef, nullptr, N_EDGES);

    // fused softmax + aggregation, one wave per node
    aggregate<<<N_NODES / 4, 256, 0, stream>>>(qf, kf, vf, ef, srcs, rowptr, out);
}